// Round 2
// baseline (967.179 us; speedup 1.0000x reference)
//
#include <hip/hip_runtime.h>

#define HIDDEN 5120
#define NEXP 160
#define NCHUNK 160                 // 5120 / 32
#define CHUNK_BYTES 20480          // hi half 10240 + lo half 10240
#define HALF_BYTES 10240
#define WBYTES (CHUNK_BYTES * NCHUNK)

typedef _Float16 f16;
typedef f16 f16x8 __attribute__((ext_vector_type(8)));
typedef float f32x4 __attribute__((ext_vector_type(4)));

__device__ __forceinline__ void async_copy16(const void* g, void* l) {
    __builtin_amdgcn_global_load_lds(
        (const __attribute__((address_space(1))) unsigned int*)g,
        (__attribute__((address_space(3))) unsigned int*)l,
        16, 0, 0);
}

// ---- K0: W fp32 -> chunked, unit-transposed f16 hi/lo (v = hi + lo/2048) ----
// Chunk kc (20480B): hi half = 10 units of 1024B (unit u = experts u*16..+15),
// within a unit the 16B block for (expert r, k-seg q) sits at (q*16 + r)*16.
// This makes the MFMA B-fragment read lane-linear in LDS (zero bank conflicts).
__global__ void k_convert_w(const float* __restrict__ W, unsigned char* __restrict__ W2) {
    int t = blockIdx.x * 256 + threadIdx.x;        // 160*640 = 102400 threads
    int e  = t / 640;
    int k8 = (t - e * 640) * 8;
    const float* src = W + (long)e * HIDDEN + k8;
    float4 v0 = *(const float4*)src;
    float4 v1 = *(const float4*)(src + 4);
    float v[8] = {v0.x, v0.y, v0.z, v0.w, v1.x, v1.y, v1.z, v1.w};
    f16x8 hi, lo;
#pragma unroll
    for (int j = 0; j < 8; ++j) {
        f16 h = (f16)v[j];
        hi[j] = h;
        lo[j] = (f16)((v[j] - (float)h) * 2048.0f);
    }
    int kc = k8 >> 5;
    int q  = (k8 >> 3) & 3;
    int u  = e >> 4;
    int r  = e & 15;
    unsigned char* base = W2 + (size_t)kc * CHUNK_BYTES + u * 1024 + (q * 16 + r) * 16;
    *(f16x8*)base = hi;
    *(f16x8*)(base + HALF_BYTES) = lo;
}

// ---- K1: fused split-f16 MFMA GEMM + softmax + group-limited top-6 ----
// 512 blocks x 128 threads (2 waves). BM=64: wave w owns rows w*32..+32 as two
// 16-row M-tiles, sharing each B-fragment across both (halves LDS read traffic).
__global__ __launch_bounds__(128, 1)
void k_gemm_gate(const float* __restrict__ X, const unsigned char* __restrict__ W2,
                 float* __restrict__ out) {
    __shared__ __align__(16) unsigned char lds[2 * CHUNK_BYTES];   // 40KB dbuf; epilogue overlays
    const int tid = threadIdx.x;
    const int w   = tid >> 6;
    const int l   = tid & 63;
    const int r16 = l & 15;
    const int q   = l >> 4;

    const long m0 = (long)blockIdx.x * 64 + w * 32;
    const float* ap0 = X + (m0 + r16) * HIDDEN + q * 8;
    const float* ap1 = ap0 + 16 * HIDDEN;

    const unsigned char* gstage = W2 + (size_t)tid * 16;
    unsigned char* lstage = lds + (tid & ~63) * 16;   // wave-uniform base (+lane*16 by HW)

    f32x4 acc0[2][10], acc1[2][10];
    const f32x4 zero = {0.f, 0.f, 0.f, 0.f};
#pragma unroll
    for (int t = 0; t < 2; ++t)
#pragma unroll
        for (int n = 0; n < 10; ++n) { acc0[t][n] = zero; acc1[t][n] = zero; }

    // prologue: stage chunk 0, prefetch A chunk 0
#pragma unroll
    for (int i = 0; i < 10; ++i)
        async_copy16(gstage + i * 2048, lstage + i * 2048);
    float4 a00 = *(const float4*)ap0, a01 = *(const float4*)(ap0 + 4);
    float4 a10 = *(const float4*)ap1, a11 = *(const float4*)(ap1 + 4);

#pragma unroll 2
    for (int kc = 0; kc < NCHUNK; ++kc) {
        __syncthreads();   // drains stage(kc) + A(kc); frees the other buffer

        float4 n00 = a00, n01 = a01, n10 = a10, n11 = a11;
        if (kc + 1 < NCHUNK) {
            const unsigned char* gs = gstage + (size_t)(kc + 1) * CHUNK_BYTES;
            unsigned char* ls = lstage + ((kc + 1) & 1) * CHUNK_BYTES;
#pragma unroll
            for (int i = 0; i < 10; ++i)
                async_copy16(gs + i * 2048, ls + i * 2048);
            n00 = *(const float4*)(ap0 + (kc + 1) * 32);
            n01 = *(const float4*)(ap0 + (kc + 1) * 32 + 4);
            n10 = *(const float4*)(ap1 + (kc + 1) * 32);
            n11 = *(const float4*)(ap1 + (kc + 1) * 32 + 4);
        }

        // convert current A regs -> hi/lo f16 fragments (2 M-tiles)
        f16x8 ahi[2], alo[2];
        {
            float av0[8] = {a00.x, a00.y, a00.z, a00.w, a01.x, a01.y, a01.z, a01.w};
            float av1[8] = {a10.x, a10.y, a10.z, a10.w, a11.x, a11.y, a11.z, a11.w};
#pragma unroll
            for (int j = 0; j < 8; ++j) {
                f16 h0 = (f16)av0[j]; ahi[0][j] = h0; alo[0][j] = (f16)((av0[j] - (float)h0) * 2048.0f);
                f16 h1 = (f16)av1[j]; ahi[1][j] = h1; alo[1][j] = (f16)((av1[j] - (float)h1) * 2048.0f);
            }
        }

        // B-fragment reads are lane-linear (l*16) thanks to the W2 unit transpose
        const unsigned char* lb = lds + (kc & 1) * CHUNK_BYTES + l * 16;
#pragma unroll
        for (int n = 0; n < 10; ++n) {
            f16x8 bhi = *(const f16x8*)(lb + n * 1024);
            f16x8 blo = *(const f16x8*)(lb + n * 1024 + HALF_BYTES);
            acc0[0][n] = __builtin_amdgcn_mfma_f32_16x16x32_f16(ahi[0], bhi, acc0[0][n], 0, 0, 0);
            acc1[0][n] = __builtin_amdgcn_mfma_f32_16x16x32_f16(alo[0], bhi, acc1[0][n], 0, 0, 0);
            acc1[0][n] = __builtin_amdgcn_mfma_f32_16x16x32_f16(ahi[0], blo, acc1[0][n], 0, 0, 0);
            acc0[1][n] = __builtin_amdgcn_mfma_f32_16x16x32_f16(ahi[1], bhi, acc0[1][n], 0, 0, 0);
            acc1[1][n] = __builtin_amdgcn_mfma_f32_16x16x32_f16(alo[1], bhi, acc1[1][n], 0, 0, 0);
            acc1[1][n] = __builtin_amdgcn_mfma_f32_16x16x32_f16(ahi[1], blo, acc1[1][n], 0, 0, 0);
        }
        a00 = n00; a01 = n01; a10 = n10; a11 = n11;
    }

    // ---- fused gate epilogue ----
    // Wave w holds full 160-expert logit rows for its 32 rows. Round-trip each
    // 16-row tile through LDS (stride 164 floats -> conflict-free), then 16
    // lanes run softmax-denominator + group-limited top-6 per row.
    float* region = (float*)lds + w * 2624;           // 16*164 floats = 10496 B per wave
#pragma unroll
    for (int t = 0; t < 2; ++t) {
        __syncthreads();
#pragma unroll
        for (int n = 0; n < 10; ++n)
#pragma unroll
            for (int rr = 0; rr < 4; ++rr)
                region[(q * 4 + rr) * 164 + n * 16 + r16] =
                    acc0[t][n][rr] + acc1[t][n][rr] * (1.0f / 2048.0f);
        __syncthreads();
        if (l < 16) {
            const float* row = region + l * 164;

            float denom = 0.f;
            float gmax[8];
#pragma unroll
            for (int g = 0; g < 8; ++g) {
                float m = -1e30f;
#pragma unroll
                for (int i = 0; i < 5; ++i) {
                    float4 v = *(const float4*)(row + g * 20 + i * 4);
                    denom += __expf(v.x) + __expf(v.y) + __expf(v.z) + __expf(v.w);
                    m = fmaxf(m, fmaxf(fmaxf(v.x, v.y), fmaxf(v.z, v.w)));
                }
                gmax[g] = m;
            }

            // top-3 groups by group-max logit (ties -> lower index, like lax.top_k)
            float b1 = -1e30f, b2 = -1e30f, b3 = -1e30f;
            int i1 = 0, i2 = 0, i3 = 0;
#pragma unroll
            for (int g = 0; g < 8; ++g) {
                float v = gmax[g];
                if (v > b1)      { b3 = b2; i3 = i2; b2 = b1; i2 = i1; b1 = v; i1 = g; }
                else if (v > b2) { b3 = b2; i3 = i2; b2 = v; i2 = g; }
                else if (v > b3) { b3 = v; i3 = g; }
            }

            // top-6 logits among the 3 selected groups (60 candidates)
            float w6[6] = {-1e30f, -1e30f, -1e30f, -1e30f, -1e30f, -1e30f};
            int gs[3] = {i1, i2, i3};
            for (int gi = 0; gi < 3; ++gi) {
                const float* grp = row + gs[gi] * 20;
#pragma unroll
                for (int i = 0; i < 20; ++i) {
                    float v = grp[i];
                    if (v > w6[5]) {
                        w6[5] = v;
#pragma unroll
                        for (int j = 5; j > 0; --j) {
                            if (w6[j] > w6[j - 1]) { float tmp = w6[j - 1]; w6[j - 1] = w6[j]; w6[j] = tmp; }
                        }
                    }
                }
            }

            float* o = out + (m0 + t * 16 + l) * 6;
#pragma unroll
            for (int j = 0; j < 6; ++j) o[j] = 16.0f * __expf(w6[j]) / denom;
        }
    }
}

extern "C" void kernel_launch(void* const* d_in, const int* in_sizes, int n_in,
                              void* d_out, int out_size, void* d_ws, size_t ws_size,
                              hipStream_t stream) {
    const float* X = (const float*)d_in[0];        // hidden_states [32768, 5120] fp32
    const float* W = (const float*)d_in[1];        // kernel [160, 5120] fp32
    float* out = (float*)d_out;                    // [32768, 6] fp32

    unsigned char* W2 = (unsigned char*)d_ws;      // 3,276,800 B converted W

    hipLaunchKernelGGL(k_convert_w, dim3(400), dim3(256), 0, stream, W, W2);
    hipLaunchKernelGGL(k_gemm_gate, dim3(512), dim3(128), 0, stream, X, W2, out);
}